// Round 1
// baseline (1468.914 us; speedup 1.0000x reference)
//
#include <hip/hip_runtime.h>

#define B_SZ 8
#define L_SZ 4096
#define H_SZ 512
#define P_SZ 512
#define M_SZ (B_SZ * L_SZ)      // 32768
#define NCH 32
#define CHUNK (L_SZ / NCH)      // 128  (= 2^7)

// ---------------------------------------------------------------------------
// ws layout (float units):
//   Bu      : float2[M*P]            (re,im interleaved; overwritten by x in scan)
//   Wre     : float[P*H]             (B_bar real plane)
//   Wim     : float[P*H]             (B_bar imag plane)
//   Lbar    : float2[P]
//   AS      : float2[P]              (Lambda_bar^CHUNK)
//   scale   : float2[P]              ((Lambda_bar-1)/Lambda)
//   carries : float2[B*NCH*P]
// total ~ 138 MB
// ---------------------------------------------------------------------------

__global__ void precompute_k(const float* __restrict__ lam_re,
                             const float* __restrict__ lam_im,
                             const float* __restrict__ log_step,
                             float2* __restrict__ Lbar,
                             float2* __restrict__ AS,
                             float2* __restrict__ scale) {
    int p = blockIdx.x * blockDim.x + threadIdx.x;
    if (p >= P_SZ) return;
    float lr = lam_re[p], li = lam_im[p];
    float dt = expf(log_step[p]);
    float zr = lr * dt, zi = li * dt;
    float er = expf(zr);
    float ar = er * cosf(zi), ai = er * sinf(zi);
    Lbar[p] = make_float2(ar, ai);
    // scale = (Lbar - 1) / Lam = (Lbar-1)*conj(Lam)/|Lam|^2
    float nr = ar - 1.0f, ni = ai;
    float d2 = lr * lr + li * li;
    scale[p] = make_float2((nr * lr + ni * li) / d2, (ni * lr - nr * li) / d2);
    // A^CHUNK via log2(CHUNK)=7 squarings
    float xr = ar, xi = ai;
    #pragma unroll
    for (int i = 0; i < 7; i++) {
        float tr = xr * xr - xi * xi;
        float ti = 2.0f * xr * xi;
        xr = tr; xi = ti;
    }
    AS[p] = make_float2(xr, xi);
}

__global__ void bbar_k(const float* __restrict__ Bre,
                       const float* __restrict__ Bim,
                       const float2* __restrict__ scale,
                       float* __restrict__ Wre,
                       float* __restrict__ Wim) {
    int idx = blockIdx.x * blockDim.x + threadIdx.x;   // over P*H
    if (idx >= P_SZ * H_SZ) return;
    int p = idx / H_SZ;
    float2 s = scale[p];
    float br = Bre[idx], bi = Bim[idx];
    Wre[idx] = s.x * br - s.y * bi;
    Wim[idx] = s.x * bi + s.y * br;
}

// GEMM1: Bu[m,p] = sum_h U[m,h] * (Wre[p,h] + i*Wim[p,h])
// 64x64 tile, BK=16, 256 threads, 4x4 per-thread, dual accumulators (re,im).
__global__ __launch_bounds__(256) void gemm1_k(const float* __restrict__ U,
                                               const float* __restrict__ Wre,
                                               const float* __restrict__ Wim,
                                               float2* __restrict__ Bu) {
    __shared__ float As[64][17];
    __shared__ float Wr[64][17];
    __shared__ float Wi[64][17];
    int tid = threadIdx.x;
    int tx = tid & 15, ty = tid >> 4;
    int m0 = blockIdx.y * 64;
    int n0 = blockIdx.x * 64;
    int lrow = tid >> 2;          // 0..63
    int lcol = (tid & 3) * 4;     // 0,4,8,12
    float accr[4][4] = {{0.f}}, acci[4][4] = {{0.f}};

    for (int k0 = 0; k0 < H_SZ; k0 += 16) {
        float4 av = *(const float4*)&U[(size_t)(m0 + lrow) * H_SZ + k0 + lcol];
        float4 wr = *(const float4*)&Wre[(size_t)(n0 + lrow) * H_SZ + k0 + lcol];
        float4 wi = *(const float4*)&Wim[(size_t)(n0 + lrow) * H_SZ + k0 + lcol];
        As[lrow][lcol + 0] = av.x; As[lrow][lcol + 1] = av.y;
        As[lrow][lcol + 2] = av.z; As[lrow][lcol + 3] = av.w;
        Wr[lrow][lcol + 0] = wr.x; Wr[lrow][lcol + 1] = wr.y;
        Wr[lrow][lcol + 2] = wr.z; Wr[lrow][lcol + 3] = wr.w;
        Wi[lrow][lcol + 0] = wi.x; Wi[lrow][lcol + 1] = wi.y;
        Wi[lrow][lcol + 2] = wi.z; Wi[lrow][lcol + 3] = wi.w;
        __syncthreads();
        #pragma unroll
        for (int k = 0; k < 16; k++) {
            float a[4], br[4], bi4[4];
            #pragma unroll
            for (int i = 0; i < 4; i++) a[i] = As[ty * 4 + i][k];
            #pragma unroll
            for (int j = 0; j < 4; j++) { br[j] = Wr[tx * 4 + j][k]; bi4[j] = Wi[tx * 4 + j][k]; }
            #pragma unroll
            for (int i = 0; i < 4; i++)
                #pragma unroll
                for (int j = 0; j < 4; j++) {
                    accr[i][j] = fmaf(a[i], br[j], accr[i][j]);
                    acci[i][j] = fmaf(a[i], bi4[j], acci[i][j]);
                }
        }
        __syncthreads();
    }
    #pragma unroll
    for (int i = 0; i < 4; i++)
        #pragma unroll
        for (int j = 0; j < 4; j++)
            Bu[(size_t)(m0 + ty * 4 + i) * P_SZ + n0 + tx * 4 + j] =
                make_float2(accr[i][j], acci[i][j]);
}

// Scan pass A: per (b, chunk, p) compute chunk summary state (starting from 0)
__global__ void scanA_k(const float2* __restrict__ Bu,
                        const float2* __restrict__ Lbar,
                        float2* __restrict__ carries) {
    int tid = blockIdx.x * blockDim.x + threadIdx.x;  // B*NCH*P
    int p  = tid & (P_SZ - 1);
    int bc = tid / P_SZ;
    int c  = bc & (NCH - 1);
    int b  = bc / NCH;
    float2 A = Lbar[p];
    const float2* src = &Bu[((size_t)(b * L_SZ + c * CHUNK)) * P_SZ + p];
    float sr = 0.f, si = 0.f;
    for (int t = 0; t < CHUNK; t++) {
        float2 v = src[(size_t)t * P_SZ];
        float nr = fmaf(A.x, sr, fmaf(-A.y, si, v.x));
        float ni = fmaf(A.x, si, fmaf(A.y, sr, v.y));
        sr = nr; si = ni;
    }
    carries[tid] = make_float2(sr, si);
}

// Scan pass B: exclusive scan over chunk summaries per (b,p)
__global__ void scanB_k(float2* __restrict__ carries,
                        const float2* __restrict__ AS) {
    int tid = blockIdx.x * blockDim.x + threadIdx.x;  // B*P
    int p = tid & (P_SZ - 1);
    int b = tid / P_SZ;
    float2 A = AS[p];
    float cr = 0.f, ci = 0.f;
    for (int c = 0; c < NCH; c++) {
        int idx = (b * NCH + c) * P_SZ + p;
        float2 t = carries[idx];
        carries[idx] = make_float2(cr, ci);
        float nr = fmaf(A.x, cr, fmaf(-A.y, ci, t.x));
        float ni = fmaf(A.x, ci, fmaf(A.y, cr, t.y));
        cr = nr; ci = ni;
    }
}

// Scan pass C: rescan chunk with carry-in, overwrite Bu with x (in-place)
__global__ void scanC_k(float2* __restrict__ Bu,
                        const float2* __restrict__ Lbar,
                        const float2* __restrict__ carries) {
    int tid = blockIdx.x * blockDim.x + threadIdx.x;  // B*NCH*P
    int p  = tid & (P_SZ - 1);
    int bc = tid / P_SZ;
    int c  = bc & (NCH - 1);
    int b  = bc / NCH;
    float2 A = Lbar[p];
    float2 x = carries[tid];
    float2* ptr = &Bu[((size_t)(b * L_SZ + c * CHUNK)) * P_SZ + p];
    for (int t = 0; t < CHUNK; t++) {
        float2 v = ptr[(size_t)t * P_SZ];
        float nr = fmaf(A.x, x.x, fmaf(-A.y, x.y, v.x));
        float ni = fmaf(A.x, x.y, fmaf(A.y, x.x, v.y));
        x.x = nr; x.y = ni;
        ptr[(size_t)t * P_SZ] = x;
    }
}

// GEMM2: Y[m,h] = 2*(sum_p Xre[m,p]*Cre[h,p] - Xim[m,p]*Cim[h,p])
__global__ __launch_bounds__(256) void gemm2_k(const float2* __restrict__ X,
                                               const float* __restrict__ Cre,
                                               const float* __restrict__ Cim,
                                               float* __restrict__ Y) {
    __shared__ float Ar[64][17];
    __shared__ float Ai[64][17];
    __shared__ float Wr[64][17];
    __shared__ float Wi[64][17];
    int tid = threadIdx.x;
    int tx = tid & 15, ty = tid >> 4;
    int m0 = blockIdx.y * 64;
    int n0 = blockIdx.x * 64;
    int lrow = tid >> 2;
    int lcol = (tid & 3) * 4;
    float acc[4][4] = {{0.f}};

    for (int k0 = 0; k0 < P_SZ; k0 += 16) {
        // X tile: 64 rows x 16 complex = 512 float4, 2 per thread
        #pragma unroll
        for (int q = 0; q < 2; q++) {
            int lin = tid + q * 256;
            int row = lin >> 3;
            int f4  = lin & 7;
            float4 v = *(const float4*)&X[(size_t)(m0 + row) * P_SZ + k0 + f4 * 2];
            Ar[row][f4 * 2]     = v.x; Ai[row][f4 * 2]     = v.y;
            Ar[row][f4 * 2 + 1] = v.z; Ai[row][f4 * 2 + 1] = v.w;
        }
        float4 wr = *(const float4*)&Cre[(size_t)(n0 + lrow) * P_SZ + k0 + lcol];
        float4 wi = *(const float4*)&Cim[(size_t)(n0 + lrow) * P_SZ + k0 + lcol];
        Wr[lrow][lcol + 0] = wr.x; Wr[lrow][lcol + 1] = wr.y;
        Wr[lrow][lcol + 2] = wr.z; Wr[lrow][lcol + 3] = wr.w;
        Wi[lrow][lcol + 0] = wi.x; Wi[lrow][lcol + 1] = wi.y;
        Wi[lrow][lcol + 2] = wi.z; Wi[lrow][lcol + 3] = wi.w;
        __syncthreads();
        #pragma unroll
        for (int k = 0; k < 16; k++) {
            float ar4[4], ai4[4], cr4[4], ci4[4];
            #pragma unroll
            for (int i = 0; i < 4; i++) { ar4[i] = Ar[ty * 4 + i][k]; ai4[i] = Ai[ty * 4 + i][k]; }
            #pragma unroll
            for (int j = 0; j < 4; j++) { cr4[j] = Wr[tx * 4 + j][k]; ci4[j] = Wi[tx * 4 + j][k]; }
            #pragma unroll
            for (int i = 0; i < 4; i++)
                #pragma unroll
                for (int j = 0; j < 4; j++) {
                    acc[i][j] = fmaf(ar4[i], cr4[j], acc[i][j]);
                    acc[i][j] = fmaf(-ai4[i], ci4[j], acc[i][j]);
                }
        }
        __syncthreads();
    }
    #pragma unroll
    for (int i = 0; i < 4; i++)
        #pragma unroll
        for (int j = 0; j < 4; j++)
            Y[(size_t)(m0 + ty * 4 + i) * H_SZ + n0 + tx * 4 + j] = 2.0f * acc[i][j];
}

extern "C" void kernel_launch(void* const* d_in, const int* in_sizes, int n_in,
                              void* d_out, int out_size, void* d_ws, size_t ws_size,
                              hipStream_t stream) {
    const float* lam_re   = (const float*)d_in[0];
    const float* lam_im   = (const float*)d_in[1];
    const float* Bre      = (const float*)d_in[2];
    const float* Bim      = (const float*)d_in[3];
    const float* Cre      = (const float*)d_in[4];
    const float* Cim      = (const float*)d_in[5];
    const float* log_step = (const float*)d_in[6];
    const float* U        = (const float*)d_in[7];
    float* Y = (float*)d_out;

    float* ws = (float*)d_ws;
    float2* Bu     = (float2*)ws;                                   // M*P float2
    float*  Wre    = ws + (size_t)2 * M_SZ * P_SZ;
    float*  Wim    = Wre + (size_t)P_SZ * H_SZ;
    float2* Lbar   = (float2*)(Wim + (size_t)P_SZ * H_SZ);
    float2* AS     = Lbar + P_SZ;
    float2* scale  = AS + P_SZ;
    float2* carries = scale + P_SZ;                                 // B*NCH*P float2

    precompute_k<<<dim3((P_SZ + 255) / 256), dim3(256), 0, stream>>>(
        lam_re, lam_im, log_step, Lbar, AS, scale);
    bbar_k<<<dim3((P_SZ * H_SZ) / 256), dim3(256), 0, stream>>>(
        Bre, Bim, scale, Wre, Wim);
    gemm1_k<<<dim3(P_SZ / 64, M_SZ / 64), dim3(256), 0, stream>>>(
        U, Wre, Wim, Bu);
    scanA_k<<<dim3((B_SZ * NCH * P_SZ) / 256), dim3(256), 0, stream>>>(
        Bu, Lbar, carries);
    scanB_k<<<dim3((B_SZ * P_SZ) / 256), dim3(256), 0, stream>>>(
        carries, AS);
    scanC_k<<<dim3((B_SZ * NCH * P_SZ) / 256), dim3(256), 0, stream>>>(
        Bu, Lbar, carries);
    gemm2_k<<<dim3(H_SZ / 64, M_SZ / 64), dim3(256), 0, stream>>>(
        Bu, Cre, Cim, Y);
}

// Round 2
// 648.142 us; speedup vs baseline: 2.2663x; 2.2663x over previous
//
#include <hip/hip_runtime.h>

#define B_SZ 8
#define L_SZ 4096
#define H_SZ 512
#define P_SZ 512
#define M_SZ (B_SZ * L_SZ)      // 32768
#define NCH 32
#define CHUNK (L_SZ / NCH)      // 128
#define PH (P_SZ * H_SZ)

typedef __attribute__((ext_vector_type(8))) __bf16 bf16x8;
typedef __attribute__((ext_vector_type(4))) float f32x4;

// RNE fp32 -> bf16 split: x ~= hi + lo, each bf16. Error ~2^-18 relative.
__device__ __forceinline__ void splitf(float x, unsigned short& h, unsigned short& l) {
    unsigned u = __float_as_uint(x);
    unsigned hr = (u + 0x7fffu + ((u >> 16) & 1u)) >> 16;
    h = (unsigned short)hr;
    float lo = x - __uint_as_float(hr << 16);       // exact (Sterbenz)
    unsigned ul = __float_as_uint(lo);
    l = (unsigned short)((ul + 0x7fffu + ((ul >> 16) & 1u)) >> 16);
}

__global__ void precompute_k(const float* __restrict__ lam_re,
                             const float* __restrict__ lam_im,
                             const float* __restrict__ log_step,
                             float2* __restrict__ Lbar,
                             float2* __restrict__ AS,
                             float2* __restrict__ scale) {
    int p = blockIdx.x * blockDim.x + threadIdx.x;
    if (p >= P_SZ) return;
    float lr = lam_re[p], li = lam_im[p];
    float dt = expf(log_step[p]);
    float zr = lr * dt, zi = li * dt;
    float er = expf(zr);
    float ar = er * cosf(zi), ai = er * sinf(zi);
    Lbar[p] = make_float2(ar, ai);
    float nr = ar - 1.0f, ni = ai;
    float d2 = lr * lr + li * li;
    scale[p] = make_float2((nr * lr + ni * li) / d2, (ni * lr - nr * li) / d2);
    float xr = ar, xi = ai;
    #pragma unroll
    for (int i = 0; i < 7; i++) {      // A^128 via squarings
        float tr = xr * xr - xi * xi;
        float ti = 2.0f * xr * xi;
        xr = tr; xi = ti;
    }
    AS[p] = make_float2(xr, xi);
}

// B_bar = scale * (Bre + i Bim), split into 4 bf16 planes [wre_h|wre_l|wim_h|wim_l]
__global__ void bbar_k(const float* __restrict__ Bre,
                       const float* __restrict__ Bim,
                       const float2* __restrict__ scale,
                       unsigned short* __restrict__ Wpl) {
    int idx = blockIdx.x * blockDim.x + threadIdx.x;
    if (idx >= PH) return;
    int p = idx / H_SZ;
    float2 s = scale[p];
    float br = Bre[idx], bi = Bim[idx];
    float wr = s.x * br - s.y * bi;
    float wi = s.x * bi + s.y * br;
    unsigned short h, l;
    splitf(wr, h, l);
    Wpl[idx] = h; Wpl[PH + idx] = l;
    splitf(wi, h, l);
    Wpl[2 * PH + idx] = h; Wpl[3 * PH + idx] = l;
}

// C planes: [cre_h|cre_l|cimn_h|cimn_l] where cimn = -Cim (so GEMM2 is pure add)
__global__ void csplit_k(const float* __restrict__ Cre,
                         const float* __restrict__ Cim,
                         unsigned short* __restrict__ Cpl) {
    int idx = blockIdx.x * blockDim.x + threadIdx.x;
    if (idx >= PH) return;
    unsigned short h, l;
    splitf(Cre[idx], h, l);
    Cpl[idx] = h; Cpl[PH + idx] = l;
    splitf(-Cim[idx], h, l);
    Cpl[2 * PH + idx] = h; Cpl[3 * PH + idx] = l;
}

// GEMM1: Bu[m,p] = sum_h U[m,h] * W[p,h]  (complex W, bf16x3 MFMA)
// block 128x64, 256 thr = 4 waves (2x2), wave does 64x32 = 4x2 MFMA tiles.
__global__ __launch_bounds__(256) void gemm1_k(const float* __restrict__ U,
                                               const unsigned short* __restrict__ Wpl,
                                               float2* __restrict__ Bu) {
    __shared__ unsigned short sUh[128 * 32];
    __shared__ unsigned short sUl[128 * 32];
    __shared__ unsigned short sW[4][64 * 32];
    const int tid = threadIdx.x;
    const int m0 = blockIdx.y * 128;
    const int n0 = blockIdx.x * 64;
    const int lane = tid & 63, wv = tid >> 6;
    const int wm = wv & 1, wn = wv >> 1;
    const int lr = lane & 15, kg = lane >> 4;

    f32x4 accr[4][2], acci[4][2];
    #pragma unroll
    for (int i = 0; i < 4; i++)
        #pragma unroll
        for (int j = 0; j < 2; j++) { accr[i][j] = (f32x4)0.0f; acci[i][j] = (f32x4)0.0f; }

    const int urow = tid >> 3, uc4 = tid & 7;     // base for U staging (q adds rows)
    const int wrow = tid >> 2, wc8 = tid & 3;     // W staging: 64 rows x 4 int4

    for (int k0 = 0; k0 < H_SZ; k0 += 32) {
        float4 ust[4];
        int4 wst[4];
        #pragma unroll
        for (int q = 0; q < 4; q++) {
            int row = urow + q * 32;
            ust[q] = *(const float4*)&U[(size_t)(m0 + row) * H_SZ + k0 + uc4 * 4];
        }
        #pragma unroll
        for (int q = 0; q < 4; q++)
            wst[q] = *(const int4*)&Wpl[(size_t)q * PH + (size_t)(n0 + wrow) * H_SZ + k0 + wc8 * 8];
        __syncthreads();
        #pragma unroll
        for (int q = 0; q < 4; q++) {
            int row = urow + q * 32;
            ushort4 hv, lv;
            splitf(ust[q].x, hv.x, lv.x);
            splitf(ust[q].y, hv.y, lv.y);
            splitf(ust[q].z, hv.z, lv.z);
            splitf(ust[q].w, hv.w, lv.w);
            *(ushort4*)&sUh[row * 32 + uc4 * 4] = hv;
            *(ushort4*)&sUl[row * 32 + uc4 * 4] = lv;
        }
        #pragma unroll
        for (int q = 0; q < 4; q++)
            *(int4*)&sW[q][wrow * 32 + wc8 * 8] = wst[q];
        __syncthreads();

        bf16x8 uh[4], ul[4];
        #pragma unroll
        for (int mi = 0; mi < 4; mi++) {
            int off = (wm * 64 + mi * 16 + lr) * 32 + kg * 8;
            uh[mi] = *(const bf16x8*)&sUh[off];
            ul[mi] = *(const bf16x8*)&sUl[off];
        }
        bf16x8 wrh[2], wrl[2], wih[2], wil[2];
        #pragma unroll
        for (int nj = 0; nj < 2; nj++) {
            int off = (wn * 32 + nj * 16 + lr) * 32 + kg * 8;
            wrh[nj] = *(const bf16x8*)&sW[0][off];
            wrl[nj] = *(const bf16x8*)&sW[1][off];
            wih[nj] = *(const bf16x8*)&sW[2][off];
            wil[nj] = *(const bf16x8*)&sW[3][off];
        }
        #pragma unroll
        for (int mi = 0; mi < 4; mi++)
            #pragma unroll
            for (int nj = 0; nj < 2; nj++) {
                accr[mi][nj] = __builtin_amdgcn_mfma_f32_16x16x32_bf16(uh[mi], wrh[nj], accr[mi][nj], 0, 0, 0);
                accr[mi][nj] = __builtin_amdgcn_mfma_f32_16x16x32_bf16(uh[mi], wrl[nj], accr[mi][nj], 0, 0, 0);
                accr[mi][nj] = __builtin_amdgcn_mfma_f32_16x16x32_bf16(ul[mi], wrh[nj], accr[mi][nj], 0, 0, 0);
                acci[mi][nj] = __builtin_amdgcn_mfma_f32_16x16x32_bf16(uh[mi], wih[nj], acci[mi][nj], 0, 0, 0);
                acci[mi][nj] = __builtin_amdgcn_mfma_f32_16x16x32_bf16(uh[mi], wil[nj], acci[mi][nj], 0, 0, 0);
                acci[mi][nj] = __builtin_amdgcn_mfma_f32_16x16x32_bf16(ul[mi], wih[nj], acci[mi][nj], 0, 0, 0);
            }
    }
    #pragma unroll
    for (int mi = 0; mi < 4; mi++)
        #pragma unroll
        for (int nj = 0; nj < 2; nj++)
            #pragma unroll
            for (int r = 0; r < 4; r++) {
                int m = m0 + wm * 64 + mi * 16 + kg * 4 + r;
                int p = n0 + wn * 32 + nj * 16 + lr;
                Bu[(size_t)m * P_SZ + p] = make_float2(accr[mi][nj][r], acci[mi][nj][r]);
            }
}

__global__ void scanA_k(const float2* __restrict__ Bu,
                        const float2* __restrict__ Lbar,
                        float2* __restrict__ carries) {
    int tid = blockIdx.x * blockDim.x + threadIdx.x;
    int p  = tid & (P_SZ - 1);
    int bc = tid / P_SZ;
    int c  = bc & (NCH - 1);
    int b  = bc / NCH;
    float2 A = Lbar[p];
    const float2* src = &Bu[((size_t)(b * L_SZ + c * CHUNK)) * P_SZ + p];
    float sr = 0.f, si = 0.f;
    for (int t = 0; t < CHUNK; t++) {
        float2 v = src[(size_t)t * P_SZ];
        float nr = fmaf(A.x, sr, fmaf(-A.y, si, v.x));
        float ni = fmaf(A.x, si, fmaf(A.y, sr, v.y));
        sr = nr; si = ni;
    }
    carries[tid] = make_float2(sr, si);
}

__global__ void scanB_k(float2* __restrict__ carries,
                        const float2* __restrict__ AS) {
    int tid = blockIdx.x * blockDim.x + threadIdx.x;
    int p = tid & (P_SZ - 1);
    int b = tid / P_SZ;
    float2 A = AS[p];
    float cr = 0.f, ci = 0.f;
    for (int c = 0; c < NCH; c++) {
        int idx = (b * NCH + c) * P_SZ + p;
        float2 t = carries[idx];
        carries[idx] = make_float2(cr, ci);
        float nr = fmaf(A.x, cr, fmaf(-A.y, ci, t.x));
        float ni = fmaf(A.x, ci, fmaf(A.y, cr, t.y));
        cr = nr; ci = ni;
    }
}

__global__ void scanC_k(float2* __restrict__ Bu,
                        const float2* __restrict__ Lbar,
                        const float2* __restrict__ carries) {
    int tid = blockIdx.x * blockDim.x + threadIdx.x;
    int p  = tid & (P_SZ - 1);
    int bc = tid / P_SZ;
    int c  = bc & (NCH - 1);
    int b  = bc / NCH;
    float2 A = Lbar[p];
    float2 x = carries[tid];
    float2* ptr = &Bu[((size_t)(b * L_SZ + c * CHUNK)) * P_SZ + p];
    for (int t = 0; t < CHUNK; t++) {
        float2 v = ptr[(size_t)t * P_SZ];
        float nr = fmaf(A.x, x.x, fmaf(-A.y, x.y, v.x));
        float ni = fmaf(A.x, x.y, fmaf(A.y, x.x, v.y));
        x.x = nr; x.y = ni;
        ptr[(size_t)t * P_SZ] = x;
    }
}

// GEMM2: Y[m,h] = 2*(sum_p Xre*Cre - Xim*Cim), X split on the fly, bf16x3 MFMA
__global__ __launch_bounds__(256) void gemm2_k(const float2* __restrict__ X,
                                               const unsigned short* __restrict__ Cpl,
                                               float* __restrict__ Y) {
    __shared__ unsigned short sXrh[128 * 32];
    __shared__ unsigned short sXrl[128 * 32];
    __shared__ unsigned short sXih[128 * 32];
    __shared__ unsigned short sXil[128 * 32];
    __shared__ unsigned short sC[4][64 * 32];
    const int tid = threadIdx.x;
    const int m0 = blockIdx.y * 128;
    const int n0 = blockIdx.x * 64;
    const int lane = tid & 63, wv = tid >> 6;
    const int wm = wv & 1, wn = wv >> 1;
    const int lr = lane & 15, kg = lane >> 4;

    f32x4 acc[4][2];
    #pragma unroll
    for (int i = 0; i < 4; i++)
        #pragma unroll
        for (int j = 0; j < 2; j++) acc[i][j] = (f32x4)0.0f;

    const int xrow = tid >> 4, xc2 = tid & 15;    // X staging: q adds 16 rows
    const int crow = tid >> 2, cc8 = tid & 3;

    for (int k0 = 0; k0 < P_SZ; k0 += 32) {
        float4 xst[8];
        int4 cst[4];
        #pragma unroll
        for (int q = 0; q < 8; q++) {
            int row = xrow + q * 16;
            xst[q] = *(const float4*)&X[(size_t)(m0 + row) * P_SZ + k0 + xc2 * 2];
        }
        #pragma unroll
        for (int q = 0; q < 4; q++)
            cst[q] = *(const int4*)&Cpl[(size_t)q * PH + (size_t)(n0 + crow) * P_SZ + k0 + cc8 * 8];
        __syncthreads();
        #pragma unroll
        for (int q = 0; q < 8; q++) {
            int row = xrow + q * 16;
            ushort2 rh, rl, ih, il;
            splitf(xst[q].x, rh.x, rl.x);
            splitf(xst[q].y, ih.x, il.x);
            splitf(xst[q].z, rh.y, rl.y);
            splitf(xst[q].w, ih.y, il.y);
            int off = row * 32 + xc2 * 2;
            *(ushort2*)&sXrh[off] = rh;
            *(ushort2*)&sXrl[off] = rl;
            *(ushort2*)&sXih[off] = ih;
            *(ushort2*)&sXil[off] = il;
        }
        #pragma unroll
        for (int q = 0; q < 4; q++)
            *(int4*)&sC[q][crow * 32 + cc8 * 8] = cst[q];
        __syncthreads();

        bf16x8 xrh[4], xrl[4], xih[4], xil[4];
        #pragma unroll
        for (int mi = 0; mi < 4; mi++) {
            int off = (wm * 64 + mi * 16 + lr) * 32 + kg * 8;
            xrh[mi] = *(const bf16x8*)&sXrh[off];
            xrl[mi] = *(const bf16x8*)&sXrl[off];
            xih[mi] = *(const bf16x8*)&sXih[off];
            xil[mi] = *(const bf16x8*)&sXil[off];
        }
        bf16x8 crh[2], crl[2], cih[2], cil[2];
        #pragma unroll
        for (int nj = 0; nj < 2; nj++) {
            int off = (wn * 32 + nj * 16 + lr) * 32 + kg * 8;
            crh[nj] = *(const bf16x8*)&sC[0][off];
            crl[nj] = *(const bf16x8*)&sC[1][off];
            cih[nj] = *(const bf16x8*)&sC[2][off];
            cil[nj] = *(const bf16x8*)&sC[3][off];
        }
        #pragma unroll
        for (int mi = 0; mi < 4; mi++)
            #pragma unroll
            for (int nj = 0; nj < 2; nj++) {
                acc[mi][nj] = __builtin_amdgcn_mfma_f32_16x16x32_bf16(xrh[mi], crh[nj], acc[mi][nj], 0, 0, 0);
                acc[mi][nj] = __builtin_amdgcn_mfma_f32_16x16x32_bf16(xrh[mi], crl[nj], acc[mi][nj], 0, 0, 0);
                acc[mi][nj] = __builtin_amdgcn_mfma_f32_16x16x32_bf16(xrl[mi], crh[nj], acc[mi][nj], 0, 0, 0);
                acc[mi][nj] = __builtin_amdgcn_mfma_f32_16x16x32_bf16(xih[mi], cih[nj], acc[mi][nj], 0, 0, 0);
                acc[mi][nj] = __builtin_amdgcn_mfma_f32_16x16x32_bf16(xih[mi], cil[nj], acc[mi][nj], 0, 0, 0);
                acc[mi][nj] = __builtin_amdgcn_mfma_f32_16x16x32_bf16(xil[mi], cih[nj], acc[mi][nj], 0, 0, 0);
            }
    }
    #pragma unroll
    for (int mi = 0; mi < 4; mi++)
        #pragma unroll
        for (int nj = 0; nj < 2; nj++)
            #pragma unroll
            for (int r = 0; r < 4; r++) {
                int m = m0 + wm * 64 + mi * 16 + kg * 4 + r;
                int h = n0 + wn * 32 + nj * 16 + lr;
                Y[(size_t)m * H_SZ + h] = 2.0f * acc[mi][nj][r];
            }
}

extern "C" void kernel_launch(void* const* d_in, const int* in_sizes, int n_in,
                              void* d_out, int out_size, void* d_ws, size_t ws_size,
                              hipStream_t stream) {
    const float* lam_re   = (const float*)d_in[0];
    const float* lam_im   = (const float*)d_in[1];
    const float* Bre      = (const float*)d_in[2];
    const float* Bim      = (const float*)d_in[3];
    const float* Cre      = (const float*)d_in[4];
    const float* Cim      = (const float*)d_in[5];
    const float* log_step = (const float*)d_in[6];
    const float* U        = (const float*)d_in[7];
    float* Y = (float*)d_out;

    char* ws = (char*)d_ws;
    float2* Bu = (float2*)ws;                                   // M*P float2 = 134.2 MB
    ws += (size_t)M_SZ * P_SZ * sizeof(float2);
    unsigned short* Wpl = (unsigned short*)ws;                  // 4 planes P*H = 2 MB
    ws += (size_t)4 * PH * sizeof(unsigned short);
    unsigned short* Cpl = (unsigned short*)ws;                  // 4 planes H*P = 2 MB
    ws += (size_t)4 * PH * sizeof(unsigned short);
    float2* Lbar = (float2*)ws;  ws += P_SZ * sizeof(float2);
    float2* AS   = (float2*)ws;  ws += P_SZ * sizeof(float2);
    float2* scale = (float2*)ws; ws += P_SZ * sizeof(float2);
    float2* carries = (float2*)ws;                              // B*NCH*P float2 = 1 MB

    precompute_k<<<dim3((P_SZ + 255) / 256), dim3(256), 0, stream>>>(
        lam_re, lam_im, log_step, Lbar, AS, scale);
    bbar_k<<<dim3(PH / 256), dim3(256), 0, stream>>>(Bre, Bim, scale, Wpl);
    csplit_k<<<dim3(PH / 256), dim3(256), 0, stream>>>(Cre, Cim, Cpl);
    gemm1_k<<<dim3(P_SZ / 64, M_SZ / 128), dim3(256), 0, stream>>>(U, Wpl, Bu);
    scanA_k<<<dim3((B_SZ * NCH * P_SZ) / 256), dim3(256), 0, stream>>>(Bu, Lbar, carries);
    scanB_k<<<dim3((B_SZ * P_SZ) / 256), dim3(256), 0, stream>>>(carries, AS);
    scanC_k<<<dim3((B_SZ * NCH * P_SZ) / 256), dim3(256), 0, stream>>>(Bu, Lbar, carries);
    gemm2_k<<<dim3(H_SZ / 64, M_SZ / 128), dim3(256), 0, stream>>>(Bu, Cpl, Y);
}

// Round 3
// 648.087 us; speedup vs baseline: 2.2665x; 1.0001x over previous
//
#include <hip/hip_runtime.h>

#define B_SZ 8
#define L_SZ 4096
#define H_SZ 512
#define P_SZ 512
#define M_SZ (B_SZ * L_SZ)      // 32768
#define NCH 32
#define CHUNK (L_SZ / NCH)      // 128
#define PH (P_SZ * H_SZ)

typedef __attribute__((ext_vector_type(8))) __bf16 bf16x8;
typedef __attribute__((ext_vector_type(4))) float f32x4;

// RNE fp32 -> bf16 split: x ~= hi + lo, each bf16. Error ~2^-18 relative.
__device__ __forceinline__ void splitf(float x, unsigned short& h, unsigned short& l) {
    unsigned u = __float_as_uint(x);
    unsigned hr = (u + 0x7fffu + ((u >> 16) & 1u)) >> 16;
    h = (unsigned short)hr;
    float lo = x - __uint_as_float(hr << 16);       // exact (Sterbenz)
    unsigned ul = __float_as_uint(lo);
    l = (unsigned short)((ul + 0x7fffu + ((ul >> 16) & 1u)) >> 16);
}

__global__ void precompute_k(const float* __restrict__ lam_re,
                             const float* __restrict__ lam_im,
                             const float* __restrict__ log_step,
                             float2* __restrict__ Lbar,
                             float2* __restrict__ AS,
                             float2* __restrict__ scale) {
    int p = blockIdx.x * blockDim.x + threadIdx.x;
    if (p >= P_SZ) return;
    float lr = lam_re[p], li = lam_im[p];
    float dt = expf(log_step[p]);
    float zr = lr * dt, zi = li * dt;
    float er = expf(zr);
    float ar = er * cosf(zi), ai = er * sinf(zi);
    Lbar[p] = make_float2(ar, ai);
    float nr = ar - 1.0f, ni = ai;
    float d2 = lr * lr + li * li;
    scale[p] = make_float2((nr * lr + ni * li) / d2, (ni * lr - nr * li) / d2);
    float xr = ar, xi = ai;
    #pragma unroll
    for (int i = 0; i < 7; i++) {      // A^128 via squarings
        float tr = xr * xr - xi * xi;
        float ti = 2.0f * xr * xi;
        xr = tr; xi = ti;
    }
    AS[p] = make_float2(xr, xi);
}

// Wpow[t][p] = Lbar[p]^(127-t)  (weights for in-GEMM chunk summary)
__global__ void wpow_k(const float2* __restrict__ Lbar,
                       float2* __restrict__ Wpow) {
    int idx = blockIdx.x * blockDim.x + threadIdx.x;   // t*P + p
    if (idx >= CHUNK * P_SZ) return;
    int p = idx & (P_SZ - 1);
    int t = idx >> 9;
    int e = CHUNK - 1 - t;
    float2 base = Lbar[p];
    float rr = 1.0f, ri = 0.0f;
    float br = base.x, bi = base.y;
    #pragma unroll
    for (int bit = 0; bit < 7; bit++) {
        if ((e >> bit) & 1) {
            float nr = rr * br - ri * bi;
            float ni = rr * bi + ri * br;
            rr = nr; ri = ni;
        }
        float sr = br * br - bi * bi;
        float si = 2.0f * br * bi;
        br = sr; bi = si;
    }
    Wpow[idx] = make_float2(rr, ri);
}

// B_bar = scale * (Bre + i Bim), split into 4 bf16 planes [wre_h|wre_l|wim_h|wim_l]
__global__ void bbar_k(const float* __restrict__ Bre,
                       const float* __restrict__ Bim,
                       const float2* __restrict__ scale,
                       unsigned short* __restrict__ Wpl) {
    int idx = blockIdx.x * blockDim.x + threadIdx.x;
    if (idx >= PH) return;
    int p = idx / H_SZ;
    float2 s = scale[p];
    float br = Bre[idx], bi = Bim[idx];
    float wr = s.x * br - s.y * bi;
    float wi = s.x * bi + s.y * br;
    unsigned short h, l;
    splitf(wr, h, l);
    Wpl[idx] = h; Wpl[PH + idx] = l;
    splitf(wi, h, l);
    Wpl[2 * PH + idx] = h; Wpl[3 * PH + idx] = l;
}

// C planes: [cre_h|cre_l|cimn_h|cimn_l] where cimn = -Cim
__global__ void csplit_k(const float* __restrict__ Cre,
                         const float* __restrict__ Cim,
                         unsigned short* __restrict__ Cpl) {
    int idx = blockIdx.x * blockDim.x + threadIdx.x;
    if (idx >= PH) return;
    unsigned short h, l;
    splitf(Cre[idx], h, l);
    Cpl[idx] = h; Cpl[PH + idx] = l;
    splitf(-Cim[idx], h, l);
    Cpl[2 * PH + idx] = h; Cpl[3 * PH + idx] = l;
}

// GEMM1 (pipelined) + fused chunk-summary (replaces scanA).
// block 128x64, 256 thr = 4 waves (2x2), wave 64x32 = 4x2 MFMA tiles.
__global__ __launch_bounds__(256) void gemm1_k(const float* __restrict__ U,
                                               const unsigned short* __restrict__ Wpl,
                                               const float2* __restrict__ Wpow,
                                               float2* __restrict__ Bu,
                                               float2* __restrict__ carries) {
    __shared__ unsigned short sUh[128 * 32];
    __shared__ unsigned short sUl[128 * 32];
    __shared__ unsigned short sW[4][64 * 32];
    const int tid = threadIdx.x;
    const int m0 = blockIdx.y * 128;          // = chunk g * 128
    const int n0 = blockIdx.x * 64;
    const int g  = blockIdx.y;                // chunk id b*NCH+c
    const int lane = tid & 63, wv = tid >> 6;
    const int wm = wv & 1, wn = wv >> 1;
    const int lr = lane & 15, kg = lane >> 4;

    f32x4 accr[4][2], acci[4][2];
    #pragma unroll
    for (int i = 0; i < 4; i++)
        #pragma unroll
        for (int j = 0; j < 2; j++) { accr[i][j] = (f32x4)0.0f; acci[i][j] = (f32x4)0.0f; }

    const int urow = tid >> 3, uc4 = tid & 7;
    const int wrow = tid >> 2, wc8 = tid & 3;

    float4 ust[4];
    int4 wst[4];
    // preload k0 = 0
    #pragma unroll
    for (int q = 0; q < 4; q++)
        ust[q] = *(const float4*)&U[(size_t)(m0 + urow + q * 32) * H_SZ + uc4 * 4];
    #pragma unroll
    for (int q = 0; q < 4; q++)
        wst[q] = *(const int4*)&Wpl[(size_t)q * PH + (size_t)(n0 + wrow) * H_SZ + wc8 * 8];

    for (int k0 = 0; k0 < H_SZ; k0 += 32) {
        __syncthreads();                       // prev iter's LDS reads done
        #pragma unroll
        for (int q = 0; q < 4; q++) {
            int row = urow + q * 32;
            ushort4 hv, lv;
            splitf(ust[q].x, hv.x, lv.x);
            splitf(ust[q].y, hv.y, lv.y);
            splitf(ust[q].z, hv.z, lv.z);
            splitf(ust[q].w, hv.w, lv.w);
            *(ushort4*)&sUh[row * 32 + uc4 * 4] = hv;
            *(ushort4*)&sUl[row * 32 + uc4 * 4] = lv;
        }
        #pragma unroll
        for (int q = 0; q < 4; q++)
            *(int4*)&sW[q][wrow * 32 + wc8 * 8] = wst[q];
        __syncthreads();
        // prefetch next k-tile: latency overlaps ds_read + MFMA below
        if (k0 + 32 < H_SZ) {
            #pragma unroll
            for (int q = 0; q < 4; q++)
                ust[q] = *(const float4*)&U[(size_t)(m0 + urow + q * 32) * H_SZ + k0 + 32 + uc4 * 4];
            #pragma unroll
            for (int q = 0; q < 4; q++)
                wst[q] = *(const int4*)&Wpl[(size_t)q * PH + (size_t)(n0 + wrow) * H_SZ + k0 + 32 + wc8 * 8];
        }

        bf16x8 uh[4], ul[4];
        #pragma unroll
        for (int mi = 0; mi < 4; mi++) {
            int off = (wm * 64 + mi * 16 + lr) * 32 + kg * 8;
            uh[mi] = *(const bf16x8*)&sUh[off];
            ul[mi] = *(const bf16x8*)&sUl[off];
        }
        bf16x8 wrh[2], wrl[2], wih[2], wil[2];
        #pragma unroll
        for (int nj = 0; nj < 2; nj++) {
            int off = (wn * 32 + nj * 16 + lr) * 32 + kg * 8;
            wrh[nj] = *(const bf16x8*)&sW[0][off];
            wrl[nj] = *(const bf16x8*)&sW[1][off];
            wih[nj] = *(const bf16x8*)&sW[2][off];
            wil[nj] = *(const bf16x8*)&sW[3][off];
        }
        #pragma unroll
        for (int mi = 0; mi < 4; mi++)
            #pragma unroll
            for (int nj = 0; nj < 2; nj++) {
                accr[mi][nj] = __builtin_amdgcn_mfma_f32_16x16x32_bf16(uh[mi], wrh[nj], accr[mi][nj], 0, 0, 0);
                accr[mi][nj] = __builtin_amdgcn_mfma_f32_16x16x32_bf16(uh[mi], wrl[nj], accr[mi][nj], 0, 0, 0);
                accr[mi][nj] = __builtin_amdgcn_mfma_f32_16x16x32_bf16(ul[mi], wrh[nj], accr[mi][nj], 0, 0, 0);
                acci[mi][nj] = __builtin_amdgcn_mfma_f32_16x16x32_bf16(uh[mi], wih[nj], acci[mi][nj], 0, 0, 0);
                acci[mi][nj] = __builtin_amdgcn_mfma_f32_16x16x32_bf16(uh[mi], wil[nj], acci[mi][nj], 0, 0, 0);
                acci[mi][nj] = __builtin_amdgcn_mfma_f32_16x16x32_bf16(ul[mi], wih[nj], acci[mi][nj], 0, 0, 0);
            }
    }

    // store Bu tile
    #pragma unroll
    for (int mi = 0; mi < 4; mi++)
        #pragma unroll
        for (int nj = 0; nj < 2; nj++)
            #pragma unroll
            for (int r = 0; r < 4; r++) {
                int m = m0 + wm * 64 + mi * 16 + kg * 4 + r;
                int p = n0 + wn * 32 + nj * 16 + lr;
                Bu[(size_t)m * P_SZ + p] = make_float2(accr[mi][nj][r], acci[mi][nj][r]);
            }

    // fused scanA: chunk summary s_p = sum_t Lbar_p^(127-t) * Bu[t,p]
    float2 part[2] = {make_float2(0.f, 0.f), make_float2(0.f, 0.f)};
    #pragma unroll
    for (int mi = 0; mi < 4; mi++)
        #pragma unroll
        for (int r = 0; r < 4; r++) {
            int t = wm * 64 + mi * 16 + kg * 4 + r;
            #pragma unroll
            for (int nj = 0; nj < 2; nj++) {
                int p = n0 + wn * 32 + nj * 16 + lr;
                float2 w = Wpow[t * P_SZ + p];
                float vr = accr[mi][nj][r], vi = acci[mi][nj][r];
                part[nj].x = fmaf(w.x, vr, fmaf(-w.y, vi, part[nj].x));
                part[nj].y = fmaf(w.x, vi, fmaf(w.y, vr, part[nj].y));
            }
        }
    __syncthreads();                           // staging LDS reusable now
    float2* red = (float2*)sUh;                // [2 wm][4 kg][64 p]
    #pragma unroll
    for (int nj = 0; nj < 2; nj++)
        red[(wm * 4 + kg) * 64 + wn * 32 + nj * 16 + lr] = part[nj];
    __syncthreads();
    if (tid < 64) {
        float2 s = make_float2(0.f, 0.f);
        #pragma unroll
        for (int q = 0; q < 8; q++) {
            float2 v = red[q * 64 + tid];
            s.x += v.x; s.y += v.y;
        }
        carries[(size_t)g * P_SZ + n0 + tid] = s;
    }
}

__global__ void scanB_k(float2* __restrict__ carries,
                        const float2* __restrict__ AS) {
    int tid = blockIdx.x * blockDim.x + threadIdx.x;
    int p = tid & (P_SZ - 1);
    int b = tid / P_SZ;
    float2 A = AS[p];
    float cr = 0.f, ci = 0.f;
    for (int c = 0; c < NCH; c++) {
        int idx = (b * NCH + c) * P_SZ + p;
        float2 t = carries[idx];
        carries[idx] = make_float2(cr, ci);
        float nr = fmaf(A.x, cr, fmaf(-A.y, ci, t.x));
        float ni = fmaf(A.x, ci, fmaf(A.y, cr, t.y));
        cr = nr; ci = ni;
    }
}

__global__ void scanC_k(float2* __restrict__ Bu,
                        const float2* __restrict__ Lbar,
                        const float2* __restrict__ carries) {
    int tid = blockIdx.x * blockDim.x + threadIdx.x;
    int p  = tid & (P_SZ - 1);
    int bc = tid / P_SZ;
    int c  = bc & (NCH - 1);
    int b  = bc / NCH;
    float2 A = Lbar[p];
    float2 x = carries[tid];
    float2* ptr = &Bu[((size_t)(b * L_SZ + c * CHUNK)) * P_SZ + p];
    for (int t = 0; t < CHUNK; t++) {
        float2 v = ptr[(size_t)t * P_SZ];
        float nr = fmaf(A.x, x.x, fmaf(-A.y, x.y, v.x));
        float ni = fmaf(A.x, x.y, fmaf(A.y, x.x, v.y));
        x.x = nr; x.y = ni;
        ptr[(size_t)t * P_SZ] = x;
    }
}

// GEMM2 (pipelined): Y[m,h] = 2*(sum_p Xre*Cre - Xim*Cim)
__global__ __launch_bounds__(256) void gemm2_k(const float2* __restrict__ X,
                                               const unsigned short* __restrict__ Cpl,
                                               float* __restrict__ Y) {
    __shared__ unsigned short sXrh[128 * 32];
    __shared__ unsigned short sXrl[128 * 32];
    __shared__ unsigned short sXih[128 * 32];
    __shared__ unsigned short sXil[128 * 32];
    __shared__ unsigned short sC[4][64 * 32];
    const int tid = threadIdx.x;
    const int m0 = blockIdx.y * 128;
    const int n0 = blockIdx.x * 64;
    const int lane = tid & 63, wv = tid >> 6;
    const int wm = wv & 1, wn = wv >> 1;
    const int lr = lane & 15, kg = lane >> 4;

    f32x4 acc[4][2];
    #pragma unroll
    for (int i = 0; i < 4; i++)
        #pragma unroll
        for (int j = 0; j < 2; j++) acc[i][j] = (f32x4)0.0f;

    const int xrow = tid >> 4, xc2 = tid & 15;
    const int crow = tid >> 2, cc8 = tid & 3;

    float4 xst[8];
    int4 cst[4];
    #pragma unroll
    for (int q = 0; q < 8; q++)
        xst[q] = *(const float4*)&X[(size_t)(m0 + xrow + q * 16) * P_SZ + xc2 * 2];
    #pragma unroll
    for (int q = 0; q < 4; q++)
        cst[q] = *(const int4*)&Cpl[(size_t)q * PH + (size_t)(n0 + crow) * P_SZ + cc8 * 8];

    for (int k0 = 0; k0 < P_SZ; k0 += 32) {
        __syncthreads();
        #pragma unroll
        for (int q = 0; q < 8; q++) {
            int row = xrow + q * 16;
            ushort2 rh, rl, ih, il;
            splitf(xst[q].x, rh.x, rl.x);
            splitf(xst[q].y, ih.x, il.x);
            splitf(xst[q].z, rh.y, rl.y);
            splitf(xst[q].w, ih.y, il.y);
            int off = row * 32 + xc2 * 2;
            *(ushort2*)&sXrh[off] = rh;
            *(ushort2*)&sXrl[off] = rl;
            *(ushort2*)&sXih[off] = ih;
            *(ushort2*)&sXil[off] = il;
        }
        #pragma unroll
        for (int q = 0; q < 4; q++)
            *(int4*)&sC[q][crow * 32 + cc8 * 8] = cst[q];
        __syncthreads();
        if (k0 + 32 < P_SZ) {
            #pragma unroll
            for (int q = 0; q < 8; q++)
                xst[q] = *(const float4*)&X[(size_t)(m0 + xrow + q * 16) * P_SZ + k0 + 32 + xc2 * 2];
            #pragma unroll
            for (int q = 0; q < 4; q++)
                cst[q] = *(const int4*)&Cpl[(size_t)q * PH + (size_t)(n0 + crow) * P_SZ + k0 + 32 + cc8 * 8];
        }

        bf16x8 xrh[4], xrl[4], xih[4], xil[4];
        #pragma unroll
        for (int mi = 0; mi < 4; mi++) {
            int off = (wm * 64 + mi * 16 + lr) * 32 + kg * 8;
            xrh[mi] = *(const bf16x8*)&sXrh[off];
            xrl[mi] = *(const bf16x8*)&sXrl[off];
            xih[mi] = *(const bf16x8*)&sXih[off];
            xil[mi] = *(const bf16x8*)&sXil[off];
        }
        bf16x8 crh[2], crl[2], cih[2], cil[2];
        #pragma unroll
        for (int nj = 0; nj < 2; nj++) {
            int off = (wn * 32 + nj * 16 + lr) * 32 + kg * 8;
            crh[nj] = *(const bf16x8*)&sC[0][off];
            crl[nj] = *(const bf16x8*)&sC[1][off];
            cih[nj] = *(const bf16x8*)&sC[2][off];
            cil[nj] = *(const bf16x8*)&sC[3][off];
        }
        #pragma unroll
        for (int mi = 0; mi < 4; mi++)
            #pragma unroll
            for (int nj = 0; nj < 2; nj++) {
                acc[mi][nj] = __builtin_amdgcn_mfma_f32_16x16x32_bf16(xrh[mi], crh[nj], acc[mi][nj], 0, 0, 0);
                acc[mi][nj] = __builtin_amdgcn_mfma_f32_16x16x32_bf16(xrh[mi], crl[nj], acc[mi][nj], 0, 0, 0);
                acc[mi][nj] = __builtin_amdgcn_mfma_f32_16x16x32_bf16(xrl[mi], crh[nj], acc[mi][nj], 0, 0, 0);
                acc[mi][nj] = __builtin_amdgcn_mfma_f32_16x16x32_bf16(xih[mi], cih[nj], acc[mi][nj], 0, 0, 0);
                acc[mi][nj] = __builtin_amdgcn_mfma_f32_16x16x32_bf16(xih[mi], cil[nj], acc[mi][nj], 0, 0, 0);
                acc[mi][nj] = __builtin_amdgcn_mfma_f32_16x16x32_bf16(xil[mi], cih[nj], acc[mi][nj], 0, 0, 0);
            }
    }
    #pragma unroll
    for (int mi = 0; mi < 4; mi++)
        #pragma unroll
        for (int nj = 0; nj < 2; nj++)
            #pragma unroll
            for (int r = 0; r < 4; r++) {
                int m = m0 + wm * 64 + mi * 16 + kg * 4 + r;
                int h = n0 + wn * 32 + nj * 16 + lr;
                Y[(size_t)m * H_SZ + h] = 2.0f * acc[mi][nj][r];
            }
}

extern "C" void kernel_launch(void* const* d_in, const int* in_sizes, int n_in,
                              void* d_out, int out_size, void* d_ws, size_t ws_size,
                              hipStream_t stream) {
    const float* lam_re   = (const float*)d_in[0];
    const float* lam_im   = (const float*)d_in[1];
    const float* Bre      = (const float*)d_in[2];
    const float* Bim      = (const float*)d_in[3];
    const float* Cre      = (const float*)d_in[4];
    const float* Cim      = (const float*)d_in[5];
    const float* log_step = (const float*)d_in[6];
    const float* U        = (const float*)d_in[7];
    float* Y = (float*)d_out;

    char* ws = (char*)d_ws;
    float2* Bu = (float2*)ws;                                   // 134.2 MB
    ws += (size_t)M_SZ * P_SZ * sizeof(float2);
    unsigned short* Wpl = (unsigned short*)ws;                  // 2 MB
    ws += (size_t)4 * PH * sizeof(unsigned short);
    unsigned short* Cpl = (unsigned short*)ws;                  // 2 MB
    ws += (size_t)4 * PH * sizeof(unsigned short);
    float2* Lbar = (float2*)ws;  ws += P_SZ * sizeof(float2);
    float2* AS   = (float2*)ws;  ws += P_SZ * sizeof(float2);
    float2* scale = (float2*)ws; ws += P_SZ * sizeof(float2);
    float2* carries = (float2*)ws;                              // 1 MB
    ws += (size_t)B_SZ * NCH * P_SZ * sizeof(float2);
    float2* Wpow = (float2*)ws;                                 // 0.5 MB

    precompute_k<<<dim3((P_SZ + 255) / 256), dim3(256), 0, stream>>>(
        lam_re, lam_im, log_step, Lbar, AS, scale);
    wpow_k<<<dim3((CHUNK * P_SZ) / 256), dim3(256), 0, stream>>>(Lbar, Wpow);
    bbar_k<<<dim3(PH / 256), dim3(256), 0, stream>>>(Bre, Bim, scale, Wpl);
    csplit_k<<<dim3(PH / 256), dim3(256), 0, stream>>>(Cre, Cim, Cpl);
    gemm1_k<<<dim3(P_SZ / 64, M_SZ / 128), dim3(256), 0, stream>>>(U, Wpl, Wpow, Bu, carries);
    scanB_k<<<dim3((B_SZ * P_SZ) / 256), dim3(256), 0, stream>>>(carries, AS);
    scanC_k<<<dim3((B_SZ * NCH * P_SZ) / 256), dim3(256), 0, stream>>>(Bu, Lbar, carries);
    gemm2_k<<<dim3(H_SZ / 64, M_SZ / 128), dim3(256), 0, stream>>>(Bu, Cpl, Y);
}

// Round 4
// 575.170 us; speedup vs baseline: 2.5539x; 1.1268x over previous
//
#include <hip/hip_runtime.h>

#define B_SZ 8
#define L_SZ 4096
#define H_SZ 512
#define P_SZ 512
#define M_SZ (B_SZ * L_SZ)      // 32768
#define NCH 32
#define CHUNK (L_SZ / NCH)      // 128
#define PH (P_SZ * H_SZ)

typedef __attribute__((ext_vector_type(8))) __bf16 bf16x8;
typedef __attribute__((ext_vector_type(4))) float f32x4;

// RNE fp32 -> bf16 split: x ~= hi + lo, each bf16. Error ~2^-18 relative.
__device__ __forceinline__ void splitf(float x, unsigned short& h, unsigned short& l) {
    unsigned u = __float_as_uint(x);
    unsigned hr = (u + 0x7fffu + ((u >> 16) & 1u)) >> 16;
    h = (unsigned short)hr;
    float lo = x - __uint_as_float(hr << 16);       // exact (Sterbenz)
    unsigned ul = __float_as_uint(lo);
    l = (unsigned short)((ul + 0x7fffu + ((ul >> 16) & 1u)) >> 16);
}

__global__ void precompute_k(const float* __restrict__ lam_re,
                             const float* __restrict__ lam_im,
                             const float* __restrict__ log_step,
                             float2* __restrict__ Lbar,
                             float2* __restrict__ AS,
                             float2* __restrict__ scale) {
    int p = blockIdx.x * blockDim.x + threadIdx.x;
    if (p >= P_SZ) return;
    float lr = lam_re[p], li = lam_im[p];
    float dt = expf(log_step[p]);
    float zr = lr * dt, zi = li * dt;
    float er = expf(zr);
    float ar = er * cosf(zi), ai = er * sinf(zi);
    Lbar[p] = make_float2(ar, ai);
    float nr = ar - 1.0f, ni = ai;
    float d2 = lr * lr + li * li;
    scale[p] = make_float2((nr * lr + ni * li) / d2, (ni * lr - nr * li) / d2);
    float xr = ar, xi = ai;
    #pragma unroll
    for (int i = 0; i < 7; i++) {      // A^128 via squarings
        float tr = xr * xr - xi * xi;
        float ti = 2.0f * xr * xi;
        xr = tr; xi = ti;
    }
    AS[p] = make_float2(xr, xi);
}

// Ppow[t][p] = Lbar[p]^(t+1)  (carry-correction coefficients, t in [0,CHUNK))
__global__ void ppow_k(const float2* __restrict__ Lbar,
                       float2* __restrict__ Ppow) {
    int idx = blockIdx.x * blockDim.x + threadIdx.x;   // t*P + p
    if (idx >= CHUNK * P_SZ) return;
    int p = idx & (P_SZ - 1);
    int t = idx >> 9;
    int e = t + 1;                                      // 1..128
    float2 base = Lbar[p];
    float rr = 1.0f, ri = 0.0f;
    float br = base.x, bi = base.y;
    #pragma unroll
    for (int bit = 0; bit < 8; bit++) {
        if ((e >> bit) & 1) {
            float nr = rr * br - ri * bi;
            float ni = rr * bi + ri * br;
            rr = nr; ri = ni;
        }
        float sr = br * br - bi * bi;
        float si = 2.0f * br * bi;
        br = sr; bi = si;
    }
    Ppow[idx] = make_float2(rr, ri);
}

// B_bar = scale * (Bre + i Bim), split into 4 bf16 planes [wre_h|wre_l|wim_h|wim_l]
__global__ void bbar_k(const float* __restrict__ Bre,
                       const float* __restrict__ Bim,
                       const float2* __restrict__ scale,
                       unsigned short* __restrict__ Wpl) {
    int idx = blockIdx.x * blockDim.x + threadIdx.x;
    if (idx >= PH) return;
    int p = idx / H_SZ;
    float2 s = scale[p];
    float br = Bre[idx], bi = Bim[idx];
    float wr = s.x * br - s.y * bi;
    float wi = s.x * bi + s.y * br;
    unsigned short h, l;
    splitf(wr, h, l);
    Wpl[idx] = h; Wpl[PH + idx] = l;
    splitf(wi, h, l);
    Wpl[2 * PH + idx] = h; Wpl[3 * PH + idx] = l;
}

// C planes: [cre_h|cre_l|cimn_h|cimn_l] where cimn = -Cim
__global__ void csplit_k(const float* __restrict__ Cre,
                         const float* __restrict__ Cim,
                         unsigned short* __restrict__ Cpl) {
    int idx = blockIdx.x * blockDim.x + threadIdx.x;
    if (idx >= PH) return;
    unsigned short h, l;
    splitf(Cre[idx], h, l);
    Cpl[idx] = h; Cpl[PH + idx] = l;
    splitf(-Cim[idx], h, l);
    Cpl[2 * PH + idx] = h; Cpl[3 * PH + idx] = l;
}

// GEMM1 (pipelined) + fused LOCAL scan over the 128-row chunk (zero carry-in).
// Writes x_local to Bu and chunk summary x_local[127] to carries.
// grid: (M/128, P/64) — blockIdx.x = m-tile so same-m blocks share an XCD.
__global__ __launch_bounds__(256) void gemm1_k(const float* __restrict__ U,
                                               const unsigned short* __restrict__ Wpl,
                                               const float2* __restrict__ Lbar,
                                               float2* __restrict__ Bu,
                                               float2* __restrict__ carries) {
    __shared__ __align__(16) char smem[65536];
    unsigned short* sUh = (unsigned short*)smem;        // 128*32 (8KB)
    unsigned short* sUl = sUh + 128 * 32;               // 8KB
    unsigned short* sW  = sUl + 128 * 32;               // 4 planes * 64*32 (16KB)
    const int tid = threadIdx.x;
    const int g  = blockIdx.x;                // chunk id b*NCH+c
    const int m0 = g * 128;
    const int n0 = blockIdx.y * 64;
    const int lane = tid & 63, wv = tid >> 6;
    const int wm = wv & 1, wn = wv >> 1;
    const int lr = lane & 15, kg = lane >> 4;

    f32x4 accr[4][2], acci[4][2];
    #pragma unroll
    for (int i = 0; i < 4; i++)
        #pragma unroll
        for (int j = 0; j < 2; j++) { accr[i][j] = (f32x4)0.0f; acci[i][j] = (f32x4)0.0f; }

    const int urow = tid >> 3, uc4 = tid & 7;
    const int wrow = tid >> 2, wc8 = tid & 3;

    float4 ust[4];
    int4 wst[4];
    #pragma unroll
    for (int q = 0; q < 4; q++)
        ust[q] = *(const float4*)&U[(size_t)(m0 + urow + q * 32) * H_SZ + uc4 * 4];
    #pragma unroll
    for (int q = 0; q < 4; q++)
        wst[q] = *(const int4*)&Wpl[(size_t)q * PH + (size_t)(n0 + wrow) * H_SZ + wc8 * 8];

    for (int k0 = 0; k0 < H_SZ; k0 += 32) {
        __syncthreads();
        #pragma unroll
        for (int q = 0; q < 4; q++) {
            int row = urow + q * 32;
            ushort4 hv, lv;
            splitf(ust[q].x, hv.x, lv.x);
            splitf(ust[q].y, hv.y, lv.y);
            splitf(ust[q].z, hv.z, lv.z);
            splitf(ust[q].w, hv.w, lv.w);
            *(ushort4*)&sUh[row * 32 + uc4 * 4] = hv;
            *(ushort4*)&sUl[row * 32 + uc4 * 4] = lv;
        }
        #pragma unroll
        for (int q = 0; q < 4; q++)
            *(int4*)&sW[q * 2048 + wrow * 32 + wc8 * 8] = wst[q];
        __syncthreads();
        if (k0 + 32 < H_SZ) {
            #pragma unroll
            for (int q = 0; q < 4; q++)
                ust[q] = *(const float4*)&U[(size_t)(m0 + urow + q * 32) * H_SZ + k0 + 32 + uc4 * 4];
            #pragma unroll
            for (int q = 0; q < 4; q++)
                wst[q] = *(const int4*)&Wpl[(size_t)q * PH + (size_t)(n0 + wrow) * H_SZ + k0 + 32 + wc8 * 8];
        }

        bf16x8 uh[4], ul[4];
        #pragma unroll
        for (int mi = 0; mi < 4; mi++) {
            int off = (wm * 64 + mi * 16 + lr) * 32 + kg * 8;
            uh[mi] = *(const bf16x8*)&sUh[off];
            ul[mi] = *(const bf16x8*)&sUl[off];
        }
        bf16x8 wrh[2], wrl[2], wih[2], wil[2];
        #pragma unroll
        for (int nj = 0; nj < 2; nj++) {
            int off = (wn * 32 + nj * 16 + lr) * 32 + kg * 8;
            wrh[nj] = *(const bf16x8*)&sW[0 * 2048 + off];
            wrl[nj] = *(const bf16x8*)&sW[1 * 2048 + off];
            wih[nj] = *(const bf16x8*)&sW[2 * 2048 + off];
            wil[nj] = *(const bf16x8*)&sW[3 * 2048 + off];
        }
        #pragma unroll
        for (int mi = 0; mi < 4; mi++)
            #pragma unroll
            for (int nj = 0; nj < 2; nj++) {
                accr[mi][nj] = __builtin_amdgcn_mfma_f32_16x16x32_bf16(uh[mi], wrh[nj], accr[mi][nj], 0, 0, 0);
                accr[mi][nj] = __builtin_amdgcn_mfma_f32_16x16x32_bf16(uh[mi], wrl[nj], accr[mi][nj], 0, 0, 0);
                accr[mi][nj] = __builtin_amdgcn_mfma_f32_16x16x32_bf16(ul[mi], wrh[nj], accr[mi][nj], 0, 0, 0);
                acci[mi][nj] = __builtin_amdgcn_mfma_f32_16x16x32_bf16(uh[mi], wih[nj], acci[mi][nj], 0, 0, 0);
                acci[mi][nj] = __builtin_amdgcn_mfma_f32_16x16x32_bf16(uh[mi], wil[nj], acci[mi][nj], 0, 0, 0);
                acci[mi][nj] = __builtin_amdgcn_mfma_f32_16x16x32_bf16(ul[mi], wih[nj], acci[mi][nj], 0, 0, 0);
            }
    }

    // ---- epilogue: local chunk scan in LDS (reuses staging LDS) ----
    __syncthreads();
    float2* xs = (float2*)smem;                // [128 t][64 p] = 64KB
    #pragma unroll
    for (int mi = 0; mi < 4; mi++)
        #pragma unroll
        for (int nj = 0; nj < 2; nj++)
            #pragma unroll
            for (int r = 0; r < 4; r++) {
                int t = wm * 64 + mi * 16 + kg * 4 + r;
                int p = wn * 32 + nj * 16 + lr;
                xs[t * 64 + p] = make_float2(accr[mi][nj][r], acci[mi][nj][r]);
            }
    __syncthreads();
    if (tid < 64) {
        float2 A = Lbar[n0 + tid];
        float xr = 0.f, xi = 0.f;
        for (int t = 0; t < CHUNK; t++) {
            float2 v = xs[t * 64 + tid];
            float nr = fmaf(A.x, xr, fmaf(-A.y, xi, v.x));
            float ni = fmaf(A.x, xi, fmaf(A.y, xr, v.y));
            xr = nr; xi = ni;
            xs[t * 64 + tid] = make_float2(xr, xi);
        }
        carries[(size_t)g * P_SZ + n0 + tid] = make_float2(xr, xi);
    }
    __syncthreads();
    const float4* xs4 = (const float4*)xs;
    #pragma unroll
    for (int it = 0; it < 16; it++) {
        int lin = tid + it * 256;
        int row = lin >> 5;                    // 32 float4 per row
        int c4  = lin & 31;
        *(float4*)&Bu[(size_t)(m0 + row) * P_SZ + n0 + c4 * 2] = xs4[lin];
    }
}

__global__ void scanB_k(float2* __restrict__ carries,
                        const float2* __restrict__ AS) {
    int tid = blockIdx.x * blockDim.x + threadIdx.x;
    int p = tid & (P_SZ - 1);
    int b = tid / P_SZ;
    float2 A = AS[p];
    float cr = 0.f, ci = 0.f;
    for (int c = 0; c < NCH; c++) {
        int idx = (b * NCH + c) * P_SZ + p;
        float2 t = carries[idx];
        carries[idx] = make_float2(cr, ci);
        float nr = fmaf(A.x, cr, fmaf(-A.y, ci, t.x));
        float ni = fmaf(A.x, ci, fmaf(A.y, cr, t.y));
        cr = nr; ci = ni;
    }
}

// GEMM2 (pipelined): Y = 2*(Xre*Cre - Xim*Cim); carry correction fused into
// staging: x[t] = x_local[t] + Lbar^(t+1)*carry[g].
// grid: (M/128, H/64) — blockIdx.x = m-tile for XCD L2 locality.
__global__ __launch_bounds__(256) void gemm2_k(const float2* __restrict__ X,
                                               const unsigned short* __restrict__ Cpl,
                                               const float2* __restrict__ Ppow,
                                               const float2* __restrict__ carries,
                                               float* __restrict__ Y) {
    __shared__ unsigned short sXrh[128 * 32];
    __shared__ unsigned short sXrl[128 * 32];
    __shared__ unsigned short sXih[128 * 32];
    __shared__ unsigned short sXil[128 * 32];
    __shared__ unsigned short sC[4][64 * 32];
    const int tid = threadIdx.x;
    const int g  = blockIdx.x;
    const int m0 = g * 128;
    const int n0 = blockIdx.y * 64;
    const int lane = tid & 63, wv = tid >> 6;
    const int wm = wv & 1, wn = wv >> 1;
    const int lr = lane & 15, kg = lane >> 4;

    f32x4 acc[4][2];
    #pragma unroll
    for (int i = 0; i < 4; i++)
        #pragma unroll
        for (int j = 0; j < 2; j++) acc[i][j] = (f32x4)0.0f;

    const int xrow = tid >> 4, xc2 = tid & 15;
    const int crow = tid >> 2, cc8 = tid & 3;

    float4 xst[8], pwst[8], cv;
    int4 cst[4];
    #pragma unroll
    for (int q = 0; q < 8; q++)
        xst[q] = *(const float4*)&X[(size_t)(m0 + xrow + q * 16) * P_SZ + xc2 * 2];
    #pragma unroll
    for (int q = 0; q < 8; q++)
        pwst[q] = *(const float4*)&Ppow[(size_t)(xrow + q * 16) * P_SZ + xc2 * 2];
    cv = *(const float4*)&carries[(size_t)g * P_SZ + xc2 * 2];
    #pragma unroll
    for (int q = 0; q < 4; q++)
        cst[q] = *(const int4*)&Cpl[(size_t)q * PH + (size_t)(n0 + crow) * P_SZ + cc8 * 8];

    for (int k0 = 0; k0 < P_SZ; k0 += 32) {
        __syncthreads();
        #pragma unroll
        for (int q = 0; q < 8; q++) {
            int row = xrow + q * 16;
            float xr0 = xst[q].x, xi0 = xst[q].y;
            float xr1 = xst[q].z, xi1 = xst[q].w;
            // carry correction: x += Lbar^(t+1) * c   (complex, 2 columns)
            xr0 = fmaf(pwst[q].x, cv.x, fmaf(-pwst[q].y, cv.y, xr0));
            xi0 = fmaf(pwst[q].x, cv.y, fmaf( pwst[q].y, cv.x, xi0));
            xr1 = fmaf(pwst[q].z, cv.z, fmaf(-pwst[q].w, cv.w, xr1));
            xi1 = fmaf(pwst[q].z, cv.w, fmaf( pwst[q].w, cv.z, xi1));
            ushort2 rh, rl, ih, il;
            splitf(xr0, rh.x, rl.x);
            splitf(xi0, ih.x, il.x);
            splitf(xr1, rh.y, rl.y);
            splitf(xi1, ih.y, il.y);
            int off = row * 32 + xc2 * 2;
            *(ushort2*)&sXrh[off] = rh;
            *(ushort2*)&sXrl[off] = rl;
            *(ushort2*)&sXih[off] = ih;
            *(ushort2*)&sXil[off] = il;
        }
        #pragma unroll
        for (int q = 0; q < 4; q++)
            *(int4*)&sC[q][crow * 32 + cc8 * 8] = cst[q];
        __syncthreads();
        if (k0 + 32 < P_SZ) {
            #pragma unroll
            for (int q = 0; q < 8; q++)
                xst[q] = *(const float4*)&X[(size_t)(m0 + xrow + q * 16) * P_SZ + k0 + 32 + xc2 * 2];
            #pragma unroll
            for (int q = 0; q < 8; q++)
                pwst[q] = *(const float4*)&Ppow[(size_t)(xrow + q * 16) * P_SZ + k0 + 32 + xc2 * 2];
            cv = *(const float4*)&carries[(size_t)g * P_SZ + k0 + 32 + xc2 * 2];
            #pragma unroll
            for (int q = 0; q < 4; q++)
                cst[q] = *(const int4*)&Cpl[(size_t)q * PH + (size_t)(n0 + crow) * P_SZ + k0 + 32 + cc8 * 8];
        }

        bf16x8 xrh[4], xrl[4], xih[4], xil[4];
        #pragma unroll
        for (int mi = 0; mi < 4; mi++) {
            int off = (wm * 64 + mi * 16 + lr) * 32 + kg * 8;
            xrh[mi] = *(const bf16x8*)&sXrh[off];
            xrl[mi] = *(const bf16x8*)&sXrl[off];
            xih[mi] = *(const bf16x8*)&sXih[off];
            xil[mi] = *(const bf16x8*)&sXil[off];
        }
        bf16x8 crh[2], crl[2], cih[2], cil[2];
        #pragma unroll
        for (int nj = 0; nj < 2; nj++) {
            int off = (wn * 32 + nj * 16 + lr) * 32 + kg * 8;
            crh[nj] = *(const bf16x8*)&sC[0][off];
            crl[nj] = *(const bf16x8*)&sC[1][off];
            cih[nj] = *(const bf16x8*)&sC[2][off];
            cil[nj] = *(const bf16x8*)&sC[3][off];
        }
        #pragma unroll
        for (int mi = 0; mi < 4; mi++)
            #pragma unroll
            for (int nj = 0; nj < 2; nj++) {
                acc[mi][nj] = __builtin_amdgcn_mfma_f32_16x16x32_bf16(xrh[mi], crh[nj], acc[mi][nj], 0, 0, 0);
                acc[mi][nj] = __builtin_amdgcn_mfma_f32_16x16x32_bf16(xrh[mi], crl[nj], acc[mi][nj], 0, 0, 0);
                acc[mi][nj] = __builtin_amdgcn_mfma_f32_16x16x32_bf16(xrl[mi], crh[nj], acc[mi][nj], 0, 0, 0);
                acc[mi][nj] = __builtin_amdgcn_mfma_f32_16x16x32_bf16(xih[mi], cih[nj], acc[mi][nj], 0, 0, 0);
                acc[mi][nj] = __builtin_amdgcn_mfma_f32_16x16x32_bf16(xih[mi], cil[nj], acc[mi][nj], 0, 0, 0);
                acc[mi][nj] = __builtin_amdgcn_mfma_f32_16x16x32_bf16(xil[mi], cih[nj], acc[mi][nj], 0, 0, 0);
            }
    }
    #pragma unroll
    for (int mi = 0; mi < 4; mi++)
        #pragma unroll
        for (int nj = 0; nj < 2; nj++)
            #pragma unroll
            for (int r = 0; r < 4; r++) {
                int m = m0 + wm * 64 + mi * 16 + kg * 4 + r;
                int h = n0 + wn * 32 + nj * 16 + lr;
                Y[(size_t)m * H_SZ + h] = 2.0f * acc[mi][nj][r];
            }
}

extern "C" void kernel_launch(void* const* d_in, const int* in_sizes, int n_in,
                              void* d_out, int out_size, void* d_ws, size_t ws_size,
                              hipStream_t stream) {
    const float* lam_re   = (const float*)d_in[0];
    const float* lam_im   = (const float*)d_in[1];
    const float* Bre      = (const float*)d_in[2];
    const float* Bim      = (const float*)d_in[3];
    const float* Cre      = (const float*)d_in[4];
    const float* Cim      = (const float*)d_in[5];
    const float* log_step = (const float*)d_in[6];
    const float* U        = (const float*)d_in[7];
    float* Y = (float*)d_out;

    char* ws = (char*)d_ws;
    float2* Bu = (float2*)ws;                                   // 134.2 MB (x_local)
    ws += (size_t)M_SZ * P_SZ * sizeof(float2);
    unsigned short* Wpl = (unsigned short*)ws;                  // 2 MB
    ws += (size_t)4 * PH * sizeof(unsigned short);
    unsigned short* Cpl = (unsigned short*)ws;                  // 2 MB
    ws += (size_t)4 * PH * sizeof(unsigned short);
    float2* Lbar = (float2*)ws;  ws += P_SZ * sizeof(float2);
    float2* AS   = (float2*)ws;  ws += P_SZ * sizeof(float2);
    float2* scale = (float2*)ws; ws += P_SZ * sizeof(float2);
    float2* carries = (float2*)ws;                              // 1 MB
    ws += (size_t)B_SZ * NCH * P_SZ * sizeof(float2);
    float2* Ppow = (float2*)ws;                                 // 0.5 MB

    precompute_k<<<dim3((P_SZ + 255) / 256), dim3(256), 0, stream>>>(
        lam_re, lam_im, log_step, Lbar, AS, scale);
    ppow_k<<<dim3((CHUNK * P_SZ) / 256), dim3(256), 0, stream>>>(Lbar, Ppow);
    bbar_k<<<dim3(PH / 256), dim3(256), 0, stream>>>(Bre, Bim, scale, Wpl);
    csplit_k<<<dim3(PH / 256), dim3(256), 0, stream>>>(Cre, Cim, Cpl);
    gemm1_k<<<dim3(M_SZ / 128, P_SZ / 64), dim3(256), 0, stream>>>(U, Wpl, Lbar, Bu, carries);
    scanB_k<<<dim3((B_SZ * P_SZ) / 256), dim3(256), 0, stream>>>(carries, AS);
    gemm2_k<<<dim3(M_SZ / 128, H_SZ / 64), dim3(256), 0, stream>>>(Bu, Cpl, Ppow, carries, Y);
}

// Round 5
// 511.647 us; speedup vs baseline: 2.8709x; 1.1242x over previous
//
#include <hip/hip_runtime.h>

#define B_SZ 8
#define L_SZ 4096
#define H_SZ 512
#define P_SZ 512
#define M_SZ (B_SZ * L_SZ)      // 32768
#define NCH 32
#define CHUNK (L_SZ / NCH)      // 128
#define PH (P_SZ * H_SZ)

typedef __attribute__((ext_vector_type(8))) __bf16 bf16x8;
typedef __attribute__((ext_vector_type(4))) float f32x4;

// RNE fp32 -> bf16 split: x ~= hi + lo, each bf16. Error ~2^-18 relative.
__device__ __forceinline__ void splitf(float x, unsigned short& h, unsigned short& l) {
    unsigned u = __float_as_uint(x);
    unsigned hr = (u + 0x7fffu + ((u >> 16) & 1u)) >> 16;
    h = (unsigned short)hr;
    float lo = x - __uint_as_float(hr << 16);       // exact (Sterbenz)
    unsigned ul = __float_as_uint(lo);
    l = (unsigned short)((ul + 0x7fffu + ((ul >> 16) & 1u)) >> 16);
}

__global__ void precompute_k(const float* __restrict__ lam_re,
                             const float* __restrict__ lam_im,
                             const float* __restrict__ log_step,
                             float2* __restrict__ Lbar,
                             float2* __restrict__ AS,
                             float2* __restrict__ scale) {
    int p = blockIdx.x * blockDim.x + threadIdx.x;
    if (p >= P_SZ) return;
    float lr = lam_re[p], li = lam_im[p];
    float dt = expf(log_step[p]);
    float zr = lr * dt, zi = li * dt;
    float er = expf(zr);
    float ar = er * cosf(zi), ai = er * sinf(zi);
    Lbar[p] = make_float2(ar, ai);
    float nr = ar - 1.0f, ni = ai;
    float d2 = lr * lr + li * li;
    scale[p] = make_float2((nr * lr + ni * li) / d2, (ni * lr - nr * li) / d2);
    float xr = ar, xi = ai;
    #pragma unroll
    for (int i = 0; i < 7; i++) {      // A^128 via squarings
        float tr = xr * xr - xi * xi;
        float ti = 2.0f * xr * xi;
        xr = tr; xi = ti;
    }
    AS[p] = make_float2(xr, xi);
}

// PpowS[r][p] = Lbar[p]^(8r+1), r in [0,16)  (64 KB, stays L2-hot)
__global__ void ppows_k(const float2* __restrict__ Lbar,
                        float2* __restrict__ PpowS) {
    int idx = blockIdx.x * blockDim.x + threadIdx.x;   // r*P + p
    if (idx >= 16 * P_SZ) return;
    int p = idx & (P_SZ - 1);
    int r = idx >> 9;
    int e = 8 * r + 1;                                  // 1..121
    float2 base = Lbar[p];
    float rr = 1.0f, ri = 0.0f;
    float br = base.x, bi = base.y;
    #pragma unroll
    for (int bit = 0; bit < 7; bit++) {
        if ((e >> bit) & 1) {
            float nr = rr * br - ri * bi;
            float ni = rr * bi + ri * br;
            rr = nr; ri = ni;
        }
        float sr = br * br - bi * bi;
        float si = 2.0f * br * bi;
        br = sr; bi = si;
    }
    PpowS[idx] = make_float2(rr, ri);
}

// B_bar = scale * (Bre + i Bim), split into 4 bf16 planes [wre_h|wre_l|wim_h|wim_l]
__global__ void bbar_k(const float* __restrict__ Bre,
                       const float* __restrict__ Bim,
                       const float2* __restrict__ scale,
                       unsigned short* __restrict__ Wpl) {
    int idx = blockIdx.x * blockDim.x + threadIdx.x;
    if (idx >= PH) return;
    int p = idx / H_SZ;
    float2 s = scale[p];
    float br = Bre[idx], bi = Bim[idx];
    float wr = s.x * br - s.y * bi;
    float wi = s.x * bi + s.y * br;
    unsigned short h, l;
    splitf(wr, h, l);
    Wpl[idx] = h; Wpl[PH + idx] = l;
    splitf(wi, h, l);
    Wpl[2 * PH + idx] = h; Wpl[3 * PH + idx] = l;
}

// C planes: [cre_h|cre_l|cimn_h|cimn_l] where cimn = -Cim
__global__ void csplit_k(const float* __restrict__ Cre,
                         const float* __restrict__ Cim,
                         unsigned short* __restrict__ Cpl) {
    int idx = blockIdx.x * blockDim.x + threadIdx.x;
    if (idx >= PH) return;
    unsigned short h, l;
    splitf(Cre[idx], h, l);
    Cpl[idx] = h; Cpl[PH + idx] = l;
    splitf(-Cim[idx], h, l);
    Cpl[2 * PH + idx] = h; Cpl[3 * PH + idx] = l;
}

// swizzle: id = (m&7) + n*8 + (m>>3)*64  ->  same-m blocks share an XCD AND
// are within a 64-id dispatch window (co-resident => L2 temporal locality).
__device__ __forceinline__ void deswizzle(int bid, int& m, int& n) {
    int xcd = bid & 7;
    n = (bid >> 3) & 7;
    m = ((bid >> 6) << 3) + xcd;
}

// GEMM1 (pipelined) + fused LOCAL scan over the 128-row chunk (zero carry-in).
__global__ __launch_bounds__(256) void gemm1_k(const float* __restrict__ U,
                                               const unsigned short* __restrict__ Wpl,
                                               const float2* __restrict__ Lbar,
                                               float2* __restrict__ Bu,
                                               float2* __restrict__ carries) {
    __shared__ __align__(16) char smem[65536];
    unsigned short* sUh = (unsigned short*)smem;        // 8KB
    unsigned short* sUl = sUh + 128 * 32;               // 8KB
    unsigned short* sW  = sUl + 128 * 32;               // 16KB
    const int tid = threadIdx.x;
    int g, nb;
    deswizzle(blockIdx.x, g, nb);
    const int m0 = g * 128;
    const int n0 = nb * 64;
    const int lane = tid & 63, wv = tid >> 6;
    const int wm = wv & 1, wn = wv >> 1;
    const int lr = lane & 15, kg = lane >> 4;

    f32x4 accr[4][2], acci[4][2];
    #pragma unroll
    for (int i = 0; i < 4; i++)
        #pragma unroll
        for (int j = 0; j < 2; j++) { accr[i][j] = (f32x4)0.0f; acci[i][j] = (f32x4)0.0f; }

    const int urow = tid >> 3, uc4 = tid & 7;
    const int wrow = tid >> 2, wc8 = tid & 3;

    float4 ust[4];
    int4 wst[4];
    #pragma unroll
    for (int q = 0; q < 4; q++)
        ust[q] = *(const float4*)&U[(size_t)(m0 + urow + q * 32) * H_SZ + uc4 * 4];
    #pragma unroll
    for (int q = 0; q < 4; q++)
        wst[q] = *(const int4*)&Wpl[(size_t)q * PH + (size_t)(n0 + wrow) * H_SZ + wc8 * 8];

    for (int k0 = 0; k0 < H_SZ; k0 += 32) {
        __syncthreads();
        #pragma unroll
        for (int q = 0; q < 4; q++) {
            int row = urow + q * 32;
            ushort4 hv, lv;
            splitf(ust[q].x, hv.x, lv.x);
            splitf(ust[q].y, hv.y, lv.y);
            splitf(ust[q].z, hv.z, lv.z);
            splitf(ust[q].w, hv.w, lv.w);
            *(ushort4*)&sUh[row * 32 + uc4 * 4] = hv;
            *(ushort4*)&sUl[row * 32 + uc4 * 4] = lv;
        }
        #pragma unroll
        for (int q = 0; q < 4; q++)
            *(int4*)&sW[q * 2048 + wrow * 32 + wc8 * 8] = wst[q];
        __syncthreads();
        if (k0 + 32 < H_SZ) {
            #pragma unroll
            for (int q = 0; q < 4; q++)
                ust[q] = *(const float4*)&U[(size_t)(m0 + urow + q * 32) * H_SZ + k0 + 32 + uc4 * 4];
            #pragma unroll
            for (int q = 0; q < 4; q++)
                wst[q] = *(const int4*)&Wpl[(size_t)q * PH + (size_t)(n0 + wrow) * H_SZ + k0 + 32 + wc8 * 8];
        }

        bf16x8 uh[4], ul[4];
        #pragma unroll
        for (int mi = 0; mi < 4; mi++) {
            int off = (wm * 64 + mi * 16 + lr) * 32 + kg * 8;
            uh[mi] = *(const bf16x8*)&sUh[off];
            ul[mi] = *(const bf16x8*)&sUl[off];
        }
        bf16x8 wrh[2], wrl[2], wih[2], wil[2];
        #pragma unroll
        for (int nj = 0; nj < 2; nj++) {
            int off = (wn * 32 + nj * 16 + lr) * 32 + kg * 8;
            wrh[nj] = *(const bf16x8*)&sW[0 * 2048 + off];
            wrl[nj] = *(const bf16x8*)&sW[1 * 2048 + off];
            wih[nj] = *(const bf16x8*)&sW[2 * 2048 + off];
            wil[nj] = *(const bf16x8*)&sW[3 * 2048 + off];
        }
        #pragma unroll
        for (int mi = 0; mi < 4; mi++)
            #pragma unroll
            for (int nj = 0; nj < 2; nj++) {
                accr[mi][nj] = __builtin_amdgcn_mfma_f32_16x16x32_bf16(uh[mi], wrh[nj], accr[mi][nj], 0, 0, 0);
                accr[mi][nj] = __builtin_amdgcn_mfma_f32_16x16x32_bf16(uh[mi], wrl[nj], accr[mi][nj], 0, 0, 0);
                accr[mi][nj] = __builtin_amdgcn_mfma_f32_16x16x32_bf16(ul[mi], wrh[nj], accr[mi][nj], 0, 0, 0);
                acci[mi][nj] = __builtin_amdgcn_mfma_f32_16x16x32_bf16(uh[mi], wih[nj], acci[mi][nj], 0, 0, 0);
                acci[mi][nj] = __builtin_amdgcn_mfma_f32_16x16x32_bf16(uh[mi], wil[nj], acci[mi][nj], 0, 0, 0);
                acci[mi][nj] = __builtin_amdgcn_mfma_f32_16x16x32_bf16(ul[mi], wih[nj], acci[mi][nj], 0, 0, 0);
            }
    }

    // ---- epilogue: local chunk scan in LDS (reuses staging LDS) ----
    __syncthreads();
    float2* xs = (float2*)smem;                // [128 t][64 p] = 64KB
    #pragma unroll
    for (int mi = 0; mi < 4; mi++)
        #pragma unroll
        for (int nj = 0; nj < 2; nj++)
            #pragma unroll
            for (int r = 0; r < 4; r++) {
                int t = wm * 64 + mi * 16 + kg * 4 + r;
                int p = wn * 32 + nj * 16 + lr;
                xs[t * 64 + p] = make_float2(accr[mi][nj][r], acci[mi][nj][r]);
            }
    __syncthreads();
    if (tid < 64) {
        float2 A = Lbar[n0 + tid];
        float xr = 0.f, xi = 0.f;
        for (int t = 0; t < CHUNK; t++) {
            float2 v = xs[t * 64 + tid];
            float nr = fmaf(A.x, xr, fmaf(-A.y, xi, v.x));
            float ni = fmaf(A.x, xi, fmaf(A.y, xr, v.y));
            xr = nr; xi = ni;
            xs[t * 64 + tid] = make_float2(xr, xi);
        }
        carries[(size_t)g * P_SZ + n0 + tid] = make_float2(xr, xi);
    }
    __syncthreads();
    const float4* xs4 = (const float4*)xs;
    #pragma unroll
    for (int it = 0; it < 16; it++) {
        int lin = tid + it * 256;
        int row = lin >> 5;                    // 32 float4 per row
        int c4  = lin & 31;
        *(float4*)&Bu[(size_t)(m0 + row) * P_SZ + n0 + c4 * 2] = xs4[lin];
    }
}

__global__ void scanB_k(float2* __restrict__ carries,
                        const float2* __restrict__ AS) {
    int tid = blockIdx.x * blockDim.x + threadIdx.x;
    int p = tid & (P_SZ - 1);
    int b = tid / P_SZ;
    float2 A = AS[p];
    float cr = 0.f, ci = 0.f;
    for (int c = 0; c < NCH; c++) {
        int idx = (b * NCH + c) * P_SZ + p;
        float2 t = carries[idx];
        carries[idx] = make_float2(cr, ci);
        float nr = fmaf(A.x, cr, fmaf(-A.y, ci, t.x));
        float ni = fmaf(A.x, ci, fmaf(A.y, cr, t.y));
        cr = nr; ci = ni;
    }
}

// GEMM2: Y = 2*(Xre*Cre - Xim*Cim); carry correction fused into staging.
// Thread owns 8 CONSECUTIVE t-rows; coefficient Lbar^(t+1) carried by one
// complex mul per row from the 64 KB stepped table PpowS[r][p]=Lbar^(8r+1).
__global__ __launch_bounds__(256) void gemm2_k(const float2* __restrict__ X,
                                               const unsigned short* __restrict__ Cpl,
                                               const float2* __restrict__ PpowS,
                                               const float2* __restrict__ Lbar,
                                               const float2* __restrict__ carries,
                                               float* __restrict__ Y) {
    __shared__ unsigned short sXrh[128 * 32];
    __shared__ unsigned short sXrl[128 * 32];
    __shared__ unsigned short sXih[128 * 32];
    __shared__ unsigned short sXil[128 * 32];
    __shared__ unsigned short sC[4][64 * 32];
    const int tid = threadIdx.x;
    int g, nb;
    deswizzle(blockIdx.x, g, nb);
    const int m0 = g * 128;
    const int n0 = nb * 64;
    const int lane = tid & 63, wv = tid >> 6;
    const int wm = wv & 1, wn = wv >> 1;
    const int lr = lane & 15, kg = lane >> 4;

    f32x4 acc[4][2];
    #pragma unroll
    for (int i = 0; i < 4; i++)
        #pragma unroll
        for (int j = 0; j < 2; j++) acc[i][j] = (f32x4)0.0f;

    const int xrow = tid >> 4, xc2 = tid & 15;   // 8 consecutive rows xrow*8+q
    const int crow = tid >> 2, cc8 = tid & 3;

    float4 xst[8], wv4, lb4, cv;
    int4 cst[4];
    #pragma unroll
    for (int q = 0; q < 8; q++)
        xst[q] = *(const float4*)&X[(size_t)(m0 + xrow * 8 + q) * P_SZ + xc2 * 2];
    wv4 = *(const float4*)&PpowS[(size_t)xrow * P_SZ + xc2 * 2];
    lb4 = *(const float4*)&Lbar[xc2 * 2];
    cv  = *(const float4*)&carries[(size_t)g * P_SZ + xc2 * 2];
    #pragma unroll
    for (int q = 0; q < 4; q++)
        cst[q] = *(const int4*)&Cpl[(size_t)q * PH + (size_t)(n0 + crow) * P_SZ + cc8 * 8];

    for (int k0 = 0; k0 < P_SZ; k0 += 32) {
        __syncthreads();
        {
            // d = Lbar^(t0+1) * c  for both p columns, then step by *Lbar
            float d0r = wv4.x * cv.x - wv4.y * cv.y;
            float d0i = wv4.x * cv.y + wv4.y * cv.x;
            float d1r = wv4.z * cv.z - wv4.w * cv.w;
            float d1i = wv4.z * cv.w + wv4.w * cv.z;
            #pragma unroll
            for (int q = 0; q < 8; q++) {
                int row = xrow * 8 + q;
                float xr0 = xst[q].x + d0r, xi0 = xst[q].y + d0i;
                float xr1 = xst[q].z + d1r, xi1 = xst[q].w + d1i;
                float t0r = d0r * lb4.x - d0i * lb4.y;
                float t0i = d0r * lb4.y + d0i * lb4.x;
                float t1r = d1r * lb4.z - d1i * lb4.w;
                float t1i = d1r * lb4.w + d1i * lb4.z;
                d0r = t0r; d0i = t0i; d1r = t1r; d1i = t1i;
                ushort2 rh, rl, ih, il;
                splitf(xr0, rh.x, rl.x);
                splitf(xi0, ih.x, il.x);
                splitf(xr1, rh.y, rl.y);
                splitf(xi1, ih.y, il.y);
                int off = row * 32 + xc2 * 2;
                *(ushort2*)&sXrh[off] = rh;
                *(ushort2*)&sXrl[off] = rl;
                *(ushort2*)&sXih[off] = ih;
                *(ushort2*)&sXil[off] = il;
            }
        }
        #pragma unroll
        for (int q = 0; q < 4; q++)
            *(int4*)&sC[q][crow * 32 + cc8 * 8] = cst[q];
        __syncthreads();
        if (k0 + 32 < P_SZ) {
            #pragma unroll
            for (int q = 0; q < 8; q++)
                xst[q] = *(const float4*)&X[(size_t)(m0 + xrow * 8 + q) * P_SZ + k0 + 32 + xc2 * 2];
            wv4 = *(const float4*)&PpowS[(size_t)xrow * P_SZ + k0 + 32 + xc2 * 2];
            lb4 = *(const float4*)&Lbar[k0 + 32 + xc2 * 2];
            cv  = *(const float4*)&carries[(size_t)g * P_SZ + k0 + 32 + xc2 * 2];
            #pragma unroll
            for (int q = 0; q < 4; q++)
                cst[q] = *(const int4*)&Cpl[(size_t)q * PH + (size_t)(n0 + crow) * P_SZ + k0 + 32 + cc8 * 8];
        }

        bf16x8 xrh[4], xrl[4], xih[4], xil[4];
        #pragma unroll
        for (int mi = 0; mi < 4; mi++) {
            int off = (wm * 64 + mi * 16 + lr) * 32 + kg * 8;
            xrh[mi] = *(const bf16x8*)&sXrh[off];
            xrl[mi] = *(const bf16x8*)&sXrl[off];
            xih[mi] = *(const bf16x8*)&sXih[off];
            xil[mi] = *(const bf16x8*)&sXil[off];
        }
        bf16x8 crh[2], crl[2], cih[2], cil[2];
        #pragma unroll
        for (int nj = 0; nj < 2; nj++) {
            int off = (wn * 32 + nj * 16 + lr) * 32 + kg * 8;
            crh[nj] = *(const bf16x8*)&sC[0][off];
            crl[nj] = *(const bf16x8*)&sC[1][off];
            cih[nj] = *(const bf16x8*)&sC[2][off];
            cil[nj] = *(const bf16x8*)&sC[3][off];
        }
        #pragma unroll
        for (int mi = 0; mi < 4; mi++)
            #pragma unroll
            for (int nj = 0; nj < 2; nj++) {
                acc[mi][nj] = __builtin_amdgcn_mfma_f32_16x16x32_bf16(xrh[mi], crh[nj], acc[mi][nj], 0, 0, 0);
                acc[mi][nj] = __builtin_amdgcn_mfma_f32_16x16x32_bf16(xrh[mi], crl[nj], acc[mi][nj], 0, 0, 0);
                acc[mi][nj] = __builtin_amdgcn_mfma_f32_16x16x32_bf16(xrl[mi], crh[nj], acc[mi][nj], 0, 0, 0);
                acc[mi][nj] = __builtin_amdgcn_mfma_f32_16x16x32_bf16(xih[mi], cih[nj], acc[mi][nj], 0, 0, 0);
                acc[mi][nj] = __builtin_amdgcn_mfma_f32_16x16x32_bf16(xih[mi], cil[nj], acc[mi][nj], 0, 0, 0);
                acc[mi][nj] = __builtin_amdgcn_mfma_f32_16x16x32_bf16(xil[mi], cih[nj], acc[mi][nj], 0, 0, 0);
            }
    }
    #pragma unroll
    for (int mi = 0; mi < 4; mi++)
        #pragma unroll
        for (int nj = 0; nj < 2; nj++)
            #pragma unroll
            for (int r = 0; r < 4; r++) {
                int m = m0 + wm * 64 + mi * 16 + kg * 4 + r;
                int h = n0 + wn * 32 + nj * 16 + lr;
                Y[(size_t)m * H_SZ + h] = 2.0f * acc[mi][nj][r];
            }
}

extern "C" void kernel_launch(void* const* d_in, const int* in_sizes, int n_in,
                              void* d_out, int out_size, void* d_ws, size_t ws_size,
                              hipStream_t stream) {
    const float* lam_re   = (const float*)d_in[0];
    const float* lam_im   = (const float*)d_in[1];
    const float* Bre      = (const float*)d_in[2];
    const float* Bim      = (const float*)d_in[3];
    const float* Cre      = (const float*)d_in[4];
    const float* Cim      = (const float*)d_in[5];
    const float* log_step = (const float*)d_in[6];
    const float* U        = (const float*)d_in[7];
    float* Y = (float*)d_out;

    char* ws = (char*)d_ws;
    float2* Bu = (float2*)ws;                                   // 134.2 MB (x_local)
    ws += (size_t)M_SZ * P_SZ * sizeof(float2);
    unsigned short* Wpl = (unsigned short*)ws;                  // 2 MB
    ws += (size_t)4 * PH * sizeof(unsigned short);
    unsigned short* Cpl = (unsigned short*)ws;                  // 2 MB
    ws += (size_t)4 * PH * sizeof(unsigned short);
    float2* Lbar = (float2*)ws;  ws += P_SZ * sizeof(float2);
    float2* AS   = (float2*)ws;  ws += P_SZ * sizeof(float2);
    float2* scale = (float2*)ws; ws += P_SZ * sizeof(float2);
    float2* carries = (float2*)ws;                              // 1 MB
    ws += (size_t)B_SZ * NCH * P_SZ * sizeof(float2);
    float2* PpowS = (float2*)ws;                                // 64 KB

    precompute_k<<<dim3((P_SZ + 255) / 256), dim3(256), 0, stream>>>(
        lam_re, lam_im, log_step, Lbar, AS, scale);
    ppows_k<<<dim3((16 * P_SZ) / 256), dim3(256), 0, stream>>>(Lbar, PpowS);
    bbar_k<<<dim3(PH / 256), dim3(256), 0, stream>>>(Bre, Bim, scale, Wpl);
    csplit_k<<<dim3(PH / 256), dim3(256), 0, stream>>>(Cre, Cim, Cpl);
    gemm1_k<<<dim3((M_SZ / 128) * (P_SZ / 64)), dim3(256), 0, stream>>>(U, Wpl, Lbar, Bu, carries);
    scanB_k<<<dim3((B_SZ * P_SZ) / 256), dim3(256), 0, stream>>>(carries, AS);
    gemm2_k<<<dim3((M_SZ / 128) * (H_SZ / 64)), dim3(256), 0, stream>>>(Bu, Cpl, PpowS, Lbar, carries, Y);
}